// Round 1
// baseline (14867.125 us; speedup 1.0000x reference)
//
#include <hip/hip_runtime.h>

#define S_LEN 16384
#define BATCH 128
#define HID   128

// tanh(z) = (e^{2z}-1)/(e^{2z}+1), e^{2z} = exp2(2*log2(e)*z).
// Clamp |z|<=9 so exp2 never overflows; tanh(9) = 1 - 2.7e-8 (< fp32 resolution of 1.0).
__device__ __forceinline__ float fast_tanh(float z) {
    z = fminf(fmaxf(z, -9.0f), 9.0f);
    float e = __builtin_amdgcn_exp2f(z * 2.8853900817779268f); // 2*log2(e)
    return (e - 1.0f) * __builtin_amdgcn_rcpf(e + 1.0f);
}

// One block per batch chain (128 chains). 128 threads = 2 waves.
// Thread j owns hidden unit j: W2 column j lives in 128 VGPRs.
__global__ __launch_bounds__(HID, 1) void ode_scan_kernel(
    const float* __restrict__ x,
    const float* __restrict__ W1, const float* __restrict__ b1,
    const float* __restrict__ W2, const float* __restrict__ b2,
    const float* __restrict__ W3, const float* __restrict__ b3,
    float* __restrict__ out)
{
    const int j  = threadIdx.x;   // hidden unit index
    const int bb = blockIdx.x;    // batch chain index

    __shared__ float lds_h1[HID];
    __shared__ float lds_part[2];

    // Per-unit weights in registers.
    const float c1  = W1[j];        // coefficient of y   (row 0 of W1)
    const float w1x = W1[HID + j];  // coefficient of x_n (row 1 of W1)
    const float b1j = b1[j];
    const float b2j = b2[j];
    const float w3j = W3[j];
    const float b3s = b3[0];

    // W2 column j -> 128 VGPRs. Row i load is coalesced across lanes.
    float w2c[HID];
#pragma unroll
    for (int i = 0; i < HID; ++i) w2c[i] = W2[i * HID + j];

    float y  = 0.0f;
    float xc = x[bb];               // x[0][bb], broadcast across lanes
    float xn;

    for (int n = 0; n < S_LEN; ++n) {
        // Prefetch next step's x (broadcast load; latency hidden under this step).
        int np1 = (n + 1 < S_LEN) ? (n + 1) : (S_LEN - 1);
        xn = x[np1 * BATCH + bb];

        // ---- layer 1: h1[j] = tanh(c1*y + (w1x*x + b1)) ----
        float ax = fmaf(w1x, xc, b1j);          // y-independent part
        float h1 = fast_tanh(fmaf(c1, y, ax));
        lds_h1[j] = h1;
        __syncthreads();                         // bar1: h1 visible to both waves

        // ---- layer 2: s2[j] = b2[j] + sum_i h1[i] * W2[i][j] ----
        float a0 = b2j, a1 = 0.0f, a2 = 0.0f, a3 = 0.0f;
#pragma unroll
        for (int i = 0; i < HID / 4; ++i) {
            float4 h = ((const float4*)lds_h1)[i];   // broadcast ds_read_b128
            a0 = fmaf(h.x, w2c[4 * i + 0], a0);
            a1 = fmaf(h.y, w2c[4 * i + 1], a1);
            a2 = fmaf(h.z, w2c[4 * i + 2], a2);
            a3 = fmaf(h.w, w2c[4 * i + 3], a3);
        }
        float h2 = fast_tanh((a0 + a1) + (a2 + a3));
        float p  = h2 * w3j;

        // ---- layer 3 reduce: full 64-lane sum via DPP (result in lane 63) ----
        // s_nop 1 covers the VALU-write -> DPP-read hazard.
        asm volatile(
            "s_nop 1\n\t"
            "v_add_f32 %0, %0, %0 row_shr:1 bound_ctrl:0\n\t"
            "s_nop 1\n\t"
            "v_add_f32 %0, %0, %0 row_shr:2 bound_ctrl:0\n\t"
            "s_nop 1\n\t"
            "v_add_f32 %0, %0, %0 row_shr:4 bank_mask:0xe\n\t"
            "s_nop 1\n\t"
            "v_add_f32 %0, %0, %0 row_shr:8 bank_mask:0xc\n\t"
            "s_nop 1\n\t"
            "v_add_f32 %0, %0, %0 row_bcast:15 row_mask:0xa\n\t"
            "s_nop 1\n\t"
            "v_add_f32 %0, %0, %0 row_bcast:31 row_mask:0xc\n\t"
            : "+v"(p));

        if ((j & 63) == 63) lds_part[j >> 6] = p;  // one partial per wave
        __syncthreads();                            // bar2: partials visible

        float v = lds_part[0] + lds_part[1];        // broadcast reads, replicated
        y = y + (v + b3s);                          // y_{n+1}, identical in all lanes

        if (j == 0) out[n * BATCH + bb] = y;        // ys[n][bb], fire-and-forget
        xc = xn;
    }
}

extern "C" void kernel_launch(void* const* d_in, const int* in_sizes, int n_in,
                              void* d_out, int out_size, void* d_ws, size_t ws_size,
                              hipStream_t stream) {
    const float* x  = (const float*)d_in[0];
    const float* W1 = (const float*)d_in[1];
    const float* b1 = (const float*)d_in[2];
    const float* W2 = (const float*)d_in[3];
    const float* b2 = (const float*)d_in[4];
    const float* W3 = (const float*)d_in[5];
    const float* b3 = (const float*)d_in[6];
    float* out = (float*)d_out;

    hipLaunchKernelGGL(ode_scan_kernel, dim3(BATCH), dim3(HID), 0, stream,
                       x, W1, b1, W2, b2, W3, b3, out);
}

// Round 2
// 12666.450 us; speedup vs baseline: 1.1737x; 1.1737x over previous
//
#include <hip/hip_runtime.h>

#define S_LEN 16384
#define BATCH 128
#define HID   128
#define CHUNK 128
#define NCHUNK (S_LEN / CHUNK)

// tanh(z) = (e^{2z}-1)/(e^{2z}+1), e^{2z} = exp2(2*log2(e)*z).
// Clamp |z|<=9: tanh(9) = 1 - 2.7e-8 (< fp32 resolution of 1.0).
__device__ __forceinline__ float fast_tanh(float z) {
    z = fminf(fmaxf(z, -9.0f), 9.0f);
    float e = __builtin_amdgcn_exp2f(z * 2.8853900817779268f); // 2*log2(e)
    return (e - 1.0f) * __builtin_amdgcn_rcpf(e + 1.0f);
}

// One block per batch chain (128 chains). 128 threads = 2 waves.
// Thread j owns hidden unit j: W2 column j pinned in 128 VGPRs.
__global__ __launch_bounds__(HID, 1) void ode_scan_kernel(
    const float* __restrict__ x,
    const float* __restrict__ W1, const float* __restrict__ b1,
    const float* __restrict__ W2, const float* __restrict__ b2,
    const float* __restrict__ W3, const float* __restrict__ b3,
    float* __restrict__ out)
{
    const int j  = threadIdx.x;   // hidden unit index
    const int bb = blockIdx.x;    // batch chain index

    __shared__ float lds_h1[HID];
    __shared__ float lds_part[2];
    __shared__ float lds_x[2][CHUNK];   // double-buffered x chunks for this chain

    const float c1  = W1[j];        // coefficient of y   (row 0 of W1)
    const float w1x = W1[HID + j];  // coefficient of x_n (row 1 of W1)
    const float b1j = b1[j];
    const float b2j = b2[j];
    const float w3j = W3[j];
    const float b3s = b3[0];

    // W2 column j -> 128 VGPRs (coalesced row loads), then PIN each element:
    // the empty-asm output is non-rematerializable, so regalloc must keep it
    // register-resident instead of re-loading W2 from global every step.
    float w2c[HID];
#pragma unroll
    for (int i = 0; i < HID; ++i) w2c[i] = W2[i * HID + j];
#pragma unroll
    for (int i = 0; i < HID; ++i) asm volatile("" : "+v"(w2c[i]));

    // Preload x chunk 0 for this chain: lds_x[0][t] = x[t][bb].
    lds_x[0][j] = x[j * BATCH + bb];
    __syncthreads();

    float y    = 0.0f;
    float ycap = 0.0f;               // per-lane captured y history (wave 0)
    float xc   = lds_x[0][0];        // x for step 0
    int   cur  = 0;

    for (int c = 0; c < NCHUNK; ++c) {
        // Refill the other buffer with the NEXT chunk (dup-load last chunk,
        // values unused). Safe: all reads of buf[cur^1] from chunk c-1 drained
        // (barrier arrival implies lgkmcnt drain); visibility to the other
        // wave is ordered by bar1 of step 0 below.
        int nb = (c + 1 < NCHUNK) ? (c + 1) : c;
        float xf = x[(nb * CHUNK + j) * BATCH + bb];
        lds_x[cur ^ 1][j] = xf;

#pragma unroll 1
        for (int s = 0; s < CHUNK; ++s) {
            const int n = c * CHUNK + s;
            // Prefetch next step's x (LDS broadcast; cross-chunk reads the
            // just-refilled buffer's entry 0 — written above, barriers since).
            float xn = (s < CHUNK - 1) ? lds_x[cur][s + 1] : lds_x[cur ^ 1][0];

            // ---- layer 1: h1[j] = tanh(c1*y + (w1x*x + b1)) ----
            float ax = fmaf(w1x, xc, b1j);
            float h1 = fast_tanh(fmaf(c1, y, ax));
            lds_h1[j] = h1;
            __syncthreads();                         // bar1

            // ---- layer 2: s2[j] = b2[j] + sum_i h1[i] * W2[i][j] ----
            float a0 = b2j, a1 = 0.0f, a2 = 0.0f, a3 = 0.0f;
#pragma unroll
            for (int i = 0; i < HID / 4; ++i) {
                float4 h = ((const float4*)lds_h1)[i];   // broadcast ds_read_b128
                a0 = fmaf(h.x, w2c[4 * i + 0], a0);
                a1 = fmaf(h.y, w2c[4 * i + 1], a1);
                a2 = fmaf(h.z, w2c[4 * i + 2], a2);
                a3 = fmaf(h.w, w2c[4 * i + 3], a3);
            }
            float h2 = fast_tanh((a0 + a1) + (a2 + a3));
            float p  = h2 * w3j;

            // ---- layer 3 reduce: 64-lane sum via DPP (result in lane 63) ----
            asm volatile(
                "s_nop 1\n\t"
                "v_add_f32 %0, %0, %0 row_shr:1 bound_ctrl:0\n\t"
                "s_nop 1\n\t"
                "v_add_f32 %0, %0, %0 row_shr:2 bound_ctrl:0\n\t"
                "s_nop 1\n\t"
                "v_add_f32 %0, %0, %0 row_shr:4 bank_mask:0xe\n\t"
                "s_nop 1\n\t"
                "v_add_f32 %0, %0, %0 row_shr:8 bank_mask:0xc\n\t"
                "s_nop 1\n\t"
                "v_add_f32 %0, %0, %0 row_bcast:15 row_mask:0xa\n\t"
                "s_nop 1\n\t"
                "v_add_f32 %0, %0, %0 row_bcast:31 row_mask:0xc\n\t"
                : "+v"(p));

            if ((j & 63) == 63) lds_part[j >> 6] = p;  // one partial per wave
            __syncthreads();                            // bar2

            float v = lds_part[0] + lds_part[1];        // broadcast reads
            y = y + (v + b3s);                          // y_{n+1}, all lanes

            // ---- batched y store: capture in lane (n&63), flush every 64 ----
            if (j < 64) {
                ycap = (j == (n & 63)) ? y : ycap;
                if ((n & 63) == 63)
                    out[(n - 63 + j) * BATCH + bb] = ycap;  // 64-lane scatter
            }
            xc = xn;
        }
        cur ^= 1;
    }
}

extern "C" void kernel_launch(void* const* d_in, const int* in_sizes, int n_in,
                              void* d_out, int out_size, void* d_ws, size_t ws_size,
                              hipStream_t stream) {
    const float* x  = (const float*)d_in[0];
    const float* W1 = (const float*)d_in[1];
    const float* b1 = (const float*)d_in[2];
    const float* W2 = (const float*)d_in[3];
    const float* b2 = (const float*)d_in[4];
    const float* W3 = (const float*)d_in[5];
    const float* b3 = (const float*)d_in[6];
    float* out = (float*)d_out;

    hipLaunchKernelGGL(ode_scan_kernel, dim3(BATCH), dim3(HID), 0, stream,
                       x, W1, b1, W2, b2, W3, b3, out);
}

// Round 3
// 9213.823 us; speedup vs baseline: 1.6136x; 1.3747x over previous
//
#include <hip/hip_runtime.h>

#define S_LEN 16384
#define BATCH 128
#define HID   128
#define NTHR  256
#define CHUNK 256
#define NCHUNK (S_LEN / CHUNK)

// tanh(z) = (e^{2z}-1)/(e^{2z}+1), e^{2z} = exp2(2*log2(e)*z).
// Clamp |z|<=9: tanh(9) = 1 - 2.7e-8 (< fp32 resolution of 1.0).
__device__ __forceinline__ float fast_tanh(float z) {
    z = fminf(fmaxf(z, -9.0f), 9.0f);
    float e = __builtin_amdgcn_exp2f(z * 2.8853900817779268f); // 2*log2(e)
    return (e - 1.0f) * __builtin_amdgcn_rcpf(e + 1.0f);
}

#define REP16(M) M(0) M(1) M(2) M(3) M(4) M(5) M(6) M(7) \
                 M(8) M(9) M(10) M(11) M(12) M(13) M(14) M(15)

// One block per batch chain (128 chains). 256 threads = 4 waves.
// Lanes 2m/2m+1 own hidden unit j = tid>>1 with K-halves k = tid&1:
// each thread holds 64 W2 weights as NAMED SCALARS (no array -> no SROA
// failure -> no scratch spill; straight-line asm pins block remat).
__global__ __launch_bounds__(NTHR, 1) void ode_scan_kernel(
    const float* __restrict__ x,
    const float* __restrict__ W1, const float* __restrict__ b1,
    const float* __restrict__ W2, const float* __restrict__ b2,
    const float* __restrict__ W3, const float* __restrict__ b3,
    float* __restrict__ out)
{
    const int tid  = threadIdx.x;
    const int bb   = blockIdx.x;     // batch chain index
    const int j    = tid >> 1;       // hidden unit index (0..127, twice)
    const int k    = tid & 1;        // K-half (i in [64k, 64k+64))
    const int koff = k << 6;

    __shared__ __align__(16) float lds_h1[HID];
    __shared__ __align__(16) float lds_part[4];
    __shared__ float lds_x[2][CHUNK];

    const float c1  = W1[j];         // coefficient of y   (row 0 of W1)
    const float w1x = W1[HID + j];   // coefficient of x_n (row 1 of W1)
    const float b1j = b1[j];
    const float b2j = b2[j];
    const float w3h = W3[j] * 0.5f;  // halved: each j contributes from 2 lanes
    const float b3s = b3[0];

    // 64 weights W2[koff+i][j], i=0..63, as named scalars pinned in VGPRs.
#define DECLW(r) \
    float w##r##0 = W2[(koff + 4*(r) + 0) * HID + j]; \
    float w##r##1 = W2[(koff + 4*(r) + 1) * HID + j]; \
    float w##r##2 = W2[(koff + 4*(r) + 2) * HID + j]; \
    float w##r##3 = W2[(koff + 4*(r) + 3) * HID + j]; \
    asm volatile("" : "+v"(w##r##0), "+v"(w##r##1), "+v"(w##r##2), "+v"(w##r##3));
    REP16(DECLW)

    // Preload x chunk 0 for this chain: lds_x[0][t] = x[t][bb].
    lds_x[0][tid] = x[tid * BATCH + bb];
    __syncthreads();

    float y    = 0.0f;
    float ycap = 0.0f;               // per-lane captured y history (wave 0)
    float xc   = lds_x[0][0];
    int   cur  = 0;

    const float4* lh4 = (const float4*)lds_h1;
    const int     hb  = k << 4;      // float4 base index of this K-half

    for (int c = 0; c < NCHUNK; ++c) {
        // Refill other buffer with next chunk (dup-load last chunk, unused).
        int nb = (c + 1 < NCHUNK) ? (c + 1) : c;
        float xf = x[(nb * CHUNK + tid) * BATCH + bb];
        lds_x[cur ^ 1][tid] = xf;

#pragma unroll 1
        for (int s = 0; s < CHUNK; ++s) {
            const int n = c * CHUNK + s;
            float xn = (s < CHUNK - 1) ? lds_x[cur][s + 1] : lds_x[cur ^ 1][0];

            // ---- layer 1: h1[j] = tanh(c1*y + (w1x*x + b1)) ----
            float h1 = fast_tanh(fmaf(c1, y, fmaf(w1x, xc, b1j)));
            lds_h1[j] = h1;                 // lane pair writes same value
            __syncthreads();                // bar1

            // ---- layer 2 (half-K): sum_{i in half} h1[i] * W2[i][j] ----
            float a0 = 0.0f, a1 = 0.0f, a2 = 0.0f, a3 = 0.0f;
#define MAC(r) { float4 h = lh4[hb + (r)]; \
            a0 = fmaf(h.x, w##r##0, a0); a1 = fmaf(h.y, w##r##1, a1); \
            a2 = fmaf(h.z, w##r##2, a2); a3 = fmaf(h.w, w##r##3, a3); }
            REP16(MAC)
            float p = (a0 + a1) + (a2 + a3);

            // Combine K-halves: add lane-partner's partial (2m <-> 2m+1).
            asm volatile(
                "s_nop 1\n\t"
                "v_add_f32 %0, %0, %0 quad_perm:[1,0,3,2] bound_ctrl:0\n\t"
                : "+v"(p));

            float h2 = fast_tanh(p + b2j);
            float q  = h2 * w3h;

            // ---- layer 3: 64-lane DPP sum (result in lane 63) ----
            asm volatile(
                "s_nop 1\n\t"
                "v_add_f32 %0, %0, %0 row_shr:1 bound_ctrl:0\n\t"
                "s_nop 1\n\t"
                "v_add_f32 %0, %0, %0 row_shr:2 bound_ctrl:0\n\t"
                "s_nop 1\n\t"
                "v_add_f32 %0, %0, %0 row_shr:4 bank_mask:0xe\n\t"
                "s_nop 1\n\t"
                "v_add_f32 %0, %0, %0 row_shr:8 bank_mask:0xc\n\t"
                "s_nop 1\n\t"
                "v_add_f32 %0, %0, %0 row_bcast:15 row_mask:0xa\n\t"
                "s_nop 1\n\t"
                "v_add_f32 %0, %0, %0 row_bcast:31 row_mask:0xc\n\t"
                : "+v"(q));

            if ((tid & 63) == 63) lds_part[tid >> 6] = q;  // 1 partial/wave
            __syncthreads();                // bar2

            float4 pr = *(const float4*)lds_part;
            y = y + (((pr.x + pr.y) + (pr.z + pr.w)) + b3s);

            // ---- batched y store: capture in lane (n&63), flush per 64 ----
            if (tid < 64) {
                ycap = (tid == (n & 63)) ? y : ycap;
                if ((n & 63) == 63)
                    out[(n - 63 + tid) * BATCH + bb] = ycap;
            }
            xc = xn;
        }
        cur ^= 1;
    }
}

extern "C" void kernel_launch(void* const* d_in, const int* in_sizes, int n_in,
                              void* d_out, int out_size, void* d_ws, size_t ws_size,
                              hipStream_t stream) {
    const float* x  = (const float*)d_in[0];
    const float* W1 = (const float*)d_in[1];
    const float* b1 = (const float*)d_in[2];
    const float* W2 = (const float*)d_in[3];
    const float* b2 = (const float*)d_in[4];
    const float* W3 = (const float*)d_in[5];
    const float* b3 = (const float*)d_in[6];
    float* out = (float*)d_out;

    hipLaunchKernelGGL(ode_scan_kernel, dim3(BATCH), dim3(NTHR), 0, stream,
                       x, W1, b1, W2, b2, W3, b3, out);
}

// Round 4
// 8255.579 us; speedup vs baseline: 1.8009x; 1.1161x over previous
//
#include <hip/hip_runtime.h>

#define S_LEN 16384
#define BATCH 128
#define HID   128
#define NTHR  512
#define CHUNK 512
#define NCHUNK (S_LEN / CHUNK)

// tanh(z) = (e^{2z}-1)/(e^{2z}+1), e^{2z} = exp2(2*log2(e)*z).
// Clamp |z|<=9: tanh(9) = 1 - 2.7e-8 (< fp32 resolution of 1.0).
__device__ __forceinline__ float fast_tanh(float z) {
    z = fminf(fmaxf(z, -9.0f), 9.0f);
    float e = __builtin_amdgcn_exp2f(z * 2.8853900817779268f); // 2*log2(e)
    return (e - 1.0f) * __builtin_amdgcn_rcpf(e + 1.0f);
}

#define REP8(M) M(0) M(1) M(2) M(3) M(4) M(5) M(6) M(7)

// One block per batch chain (128 chains). 512 threads = 8 waves (2/SIMD).
// Thread (j = tid>>2, q = tid&3) owns K-quarter q of hidden unit j:
// 32 W2 weights as named scalars (~60 live VGPRs -> fits ANY regalloc
// target, no spill possible). h1 is stored in 4 per-quarter LDS copies at
// 36-float stride: quarter q's ds_read_b128 hits banks 4q+4r..4q+4r+3,
// disjoint across q -> zero bank conflicts (round-3 had 5.4e8 = 256 cyc/step).
__global__ __launch_bounds__(NTHR, 2) void ode_scan_kernel(
    const float* __restrict__ x,
    const float* __restrict__ W1, const float* __restrict__ b1,
    const float* __restrict__ W2, const float* __restrict__ b2,
    const float* __restrict__ W3, const float* __restrict__ b3,
    float* __restrict__ out)
{
    const int tid = threadIdx.x;
    const int bb  = blockIdx.x;      // batch chain index
    const int j   = tid >> 2;        // hidden unit index (0..127, 4x)
    const int q   = tid & 3;         // K-quarter (i in [32q, 32q+32))

    __shared__ __align__(16) float lds_h[4 * 36];   // quarter q at 36q..36q+31
    __shared__ __align__(16) float lds_part[8];
    __shared__ float lds_x[2][CHUNK];

    const float c1  = W1[j];         // coefficient of y   (row 0 of W1)
    const float w1x = W1[HID + j];   // coefficient of x_n (row 1 of W1)
    const float b1j = b1[j];
    const float b2j = b2[j];
    const float w3q = W3[j] * 0.25f; // quartered: each j appears in 4 lanes
    const float b3s = b3[0];

    // h1[j] belongs to quarter j>>5; the lane with q == j>>5 writes it.
    const int  wq     = j >> 5;
    const bool writer = (q == wq);
    const int  wslot  = 36 * wq + (j & 31);

    // 32 weights W2[32q + 4r + c][j] as named scalars, pinned straight-line.
#define DECLW(r) \
    float w##r##0 = W2[((q << 5) + 4*(r) + 0) * HID + j]; \
    float w##r##1 = W2[((q << 5) + 4*(r) + 1) * HID + j]; \
    float w##r##2 = W2[((q << 5) + 4*(r) + 2) * HID + j]; \
    float w##r##3 = W2[((q << 5) + 4*(r) + 3) * HID + j]; \
    asm volatile("" : "+v"(w##r##0), "+v"(w##r##1), "+v"(w##r##2), "+v"(w##r##3));
    REP8(DECLW)

    // Preload x chunk 0 for this chain: lds_x[0][t] = x[t][bb].
    lds_x[0][tid] = x[tid * BATCH + bb];
    __syncthreads();

    float y    = 0.0f;
    float ycap = 0.0f;               // per-lane captured y history (wave 0)
    float xc   = lds_x[0][0];
    int   cur  = 0;

    const float4* lh4q = ((const float4*)lds_h) + 9 * q;  // 36 floats = 9 float4

    for (int c = 0; c < NCHUNK; ++c) {
        // Refill other buffer with next chunk (dup-load last chunk, unused).
        int nb = (c + 1 < NCHUNK) ? (c + 1) : c;
        float xf = x[(nb * CHUNK + tid) * BATCH + bb];
        lds_x[cur ^ 1][tid] = xf;

#pragma unroll 1
        for (int s = 0; s < CHUNK; ++s) {
            const int n = c * CHUNK + s;
            float xn = (s < CHUNK - 1) ? lds_x[cur][s + 1] : lds_x[cur ^ 1][0];

            // ---- layer 1: h1[j] = tanh(c1*y + (w1x*x + b1)) ----
            float h1 = fast_tanh(fmaf(c1, y, fmaf(w1x, xc, b1j)));
            if (writer) lds_h[wslot] = h1;   // 16 lanes/wave, distinct banks
            __syncthreads();                 // bar1

            // ---- layer 2 (quarter-K): sum_{i in q} h1[i] * W2[i][j] ----
            float a0 = 0.0f, a1 = 0.0f, a2 = 0.0f, a3 = 0.0f;
#define MACQ(r) { float4 h = lh4q[r]; \
            a0 = fmaf(h.x, w##r##0, a0); a1 = fmaf(h.y, w##r##1, a1); \
            a2 = fmaf(h.z, w##r##2, a2); a3 = fmaf(h.w, w##r##3, a3); }
            REP8(MACQ)
            float p = (a0 + a1) + (a2 + a3);

            // Combine K-quarters across the quad: xor1 then xor2.
            asm volatile(
                "s_nop 1\n\t"
                "v_add_f32 %0, %0, %0 quad_perm:[1,0,3,2] bound_ctrl:0\n\t"
                "s_nop 1\n\t"
                "v_add_f32 %0, %0, %0 quad_perm:[2,3,0,1] bound_ctrl:0\n\t"
                : "+v"(p));

            float h2 = fast_tanh(p + b2j);
            float qv = h2 * w3q;

            // ---- layer 3: 64-lane DPP sum (result in lane 63) ----
            asm volatile(
                "s_nop 1\n\t"
                "v_add_f32 %0, %0, %0 row_shr:1 bound_ctrl:0\n\t"
                "s_nop 1\n\t"
                "v_add_f32 %0, %0, %0 row_shr:2 bound_ctrl:0\n\t"
                "s_nop 1\n\t"
                "v_add_f32 %0, %0, %0 row_shr:4 bank_mask:0xe\n\t"
                "s_nop 1\n\t"
                "v_add_f32 %0, %0, %0 row_shr:8 bank_mask:0xc\n\t"
                "s_nop 1\n\t"
                "v_add_f32 %0, %0, %0 row_bcast:15 row_mask:0xa\n\t"
                "s_nop 1\n\t"
                "v_add_f32 %0, %0, %0 row_bcast:31 row_mask:0xc\n\t"
                : "+v"(qv));

            if ((tid & 63) == 63) lds_part[tid >> 6] = qv;  // 1 partial/wave
            __syncthreads();                 // bar2

            float4 pa = ((const float4*)lds_part)[0];
            float4 pb = ((const float4*)lds_part)[1];
            float  v  = ((pa.x + pa.y) + (pa.z + pa.w))
                      + ((pb.x + pb.y) + (pb.z + pb.w));
            y = y + (v + b3s);               // y_{n+1}, identical in all lanes

            // ---- batched y store: capture in lane (n&63), flush per 64 ----
            if (tid < 64) {
                ycap = (tid == (n & 63)) ? y : ycap;
                if ((n & 63) == 63)
                    out[(n - 63 + tid) * BATCH + bb] = ycap;
            }
            xc = xn;
        }
        cur ^= 1;
    }
}

extern "C" void kernel_launch(void* const* d_in, const int* in_sizes, int n_in,
                              void* d_out, int out_size, void* d_ws, size_t ws_size,
                              hipStream_t stream) {
    const float* x  = (const float*)d_in[0];
    const float* W1 = (const float*)d_in[1];
    const float* b1 = (const float*)d_in[2];
    const float* W2 = (const float*)d_in[3];
    const float* b2 = (const float*)d_in[4];
    const float* W3 = (const float*)d_in[5];
    const float* b3 = (const float*)d_in[6];
    float* out = (float*)d_out;

    hipLaunchKernelGGL(ode_scan_kernel, dim3(BATCH), dim3(NTHR), 0, stream,
                       x, W1, b1, W2, b2, W3, b3, out);
}